// Round 1
// baseline (134.402 us; speedup 1.0000x reference)
//
#include <hip/hip_runtime.h>

// x shape (8,32,256,256) float32 holding exact integers 0..255; K=3, stride 1, no pad.
#define B_   8
#define C_   32
#define H_   256
#define W_   256
#define BC_  (B_ * C_)
#define HO_  (H_ - 2)           // 254
#define WO_  (W_ - 2)           // 254
#define NIN_  (BC_ * H_ * W_)   // 16,777,216
#define NBINS 256
#define HCOLS 16                // sub-histogram columns (LDS-atomic aliasing ~2-way = free)
#define HBLOCKS 1024            // NIN_/4 = HBLOCKS*256*16 exactly

// v5: (a) hist also emits a uint8 shadow copy of x (values are exact 0..255), so the
// pool pass reads 1 B/elem instead of 4 B/elem (73 MB -> 18 MB, L3-hot from the write);
// (b) zero_hist launch and all device atomics removed: reduce stores 8 plain partial
// rows, every pool block sums them (8 KB L2-broadcast reads, free).
__device__ int g_hist8[8 * NBINS];        // 8 partial final histograms (reduce output)
__device__ int g_part[HBLOCKS * NBINS];   // 1 MB, fully overwritten each call
__device__ unsigned char g_u8[NIN_];      // 16 MB u8 shadow of x, fully overwritten

__global__ __launch_bounds__(256) void hist_kernel(const float* __restrict__ x) {
    __shared__ int sh[NBINS * HCOLS];   // 16 KB
    const int t = threadIdx.x;
    for (int i = t; i < NBINS * HCOLS; i += 256) sh[i] = 0;
    __syncthreads();

    const int col = t & (HCOLS - 1);
    const float4* x4 = (const float4*)x;
    uchar4* u4 = (uchar4*)g_u8;
    const int stride = HBLOCKS * 256;          // 262144 float4s
    float4 v[8];
#pragma unroll
    for (int half = 0; half < 2; ++half) {
        const int base = blockIdx.x * 256 + t + half * 8 * stride;
#pragma unroll
        for (int k = 0; k < 8; ++k) v[k] = x4[base + k * stride];  // 8 loads in flight
#pragma unroll
        for (int k = 0; k < 8; ++k) {
            const int ix = (int)v[k].x, iy = (int)v[k].y, iz = (int)v[k].z, iw = (int)v[k].w;
            u4[base + k * stride] = make_uchar4((unsigned char)ix, (unsigned char)iy,
                                                (unsigned char)iz, (unsigned char)iw);
            atomicAdd(&sh[ix * HCOLS + col], 1);
            atomicAdd(&sh[iy * HCOLS + col], 1);
            atomicAdd(&sh[iz * HCOLS + col], 1);
            atomicAdd(&sh[iw * HCOLS + col], 1);
        }
    }
    __syncthreads();

    // Per-bin column sum, rotated so bank = (17t+c) mod 32 (2-way = free); plain store.
    int s0 = 0;
#pragma unroll
    for (int c = 0; c < HCOLS; ++c) {
        const int cc = (c + t) & (HCOLS - 1);
        s0 += sh[t * HCOLS + cc];
    }
    g_part[blockIdx.x * NBINS + t] = s0;
}

// 8 blocks x 256 threads: block j sums partial rows [j*128, j*128+128) (coalesced,
// unroll-8 MLP), then ONE plain store per thread into its own g_hist8 row.
__global__ __launch_bounds__(256) void reduce_kernel() {
    const int t = threadIdx.x;
    const int r0 = blockIdx.x * (HBLOCKS / 8);
    int s = 0;
#pragma unroll 8
    for (int i = 0; i < HBLOCKS / 8; ++i) s += g_part[(r0 + i) * NBINS + t];
    g_hist8[blockIdx.x * NBINS + t] = s;
}

// Block = one (bc, 16-output-row strip). Sum the 8 partial histograms (L2-hot
// broadcast), build key table (key = (count<<8)|value), load 18x256 u8 input tile
// (1 B/elem, L3-hot), translate once per input element to keys in LDS. Compute reads
// keys stride-1 (2-way bank alias = free) with 3-register row rotation: 3 new LDS
// reads per output. Argmin on (key & ~255) strict '<' == exact positional first-min
// (row-major di,dj — matches jnp.argmin).
__global__ __launch_bounds__(256) void pool_kernel(float* __restrict__ out) {
    __shared__ int key_s[NBINS];
    __shared__ int tile[18 * W_];   // 18 KB
    const int t = threadIdx.x;
    int h = 0;
#pragma unroll
    for (int j = 0; j < 8; ++j) h += g_hist8[j * NBINS + t];
    key_s[t] = (h << 8) | t;
    __syncthreads();

    const int bc = blockIdx.x >> 4;
    const int s  = blockIdx.x & 15;
    const int r0 = s * 16;
    const int rows_out = (r0 + 16 <= HO_) ? 16 : (HO_ - r0);  // 16, last strip 14
    const int rows_in  = rows_out + 2;                        // 18 / 16 (fits H_)

    const uchar4* xin = (const uchar4*)(g_u8 + ((long long)bc * H_ + r0) * W_);
    const int nf4 = rows_in * (W_ / 4);
    for (int idx = t; idx < nf4; idx += 256) {
        uchar4 v = xin[idx];
        int4 k;
        k.x = key_s[v.x];
        k.y = key_s[v.y];
        k.z = key_s[v.z];
        k.w = key_s[v.w];
        ((int4*)tile)[idx] = k;
    }
    __syncthreads();

    if (t >= WO_) return;   // no further barriers below

    int a0 = tile[t],        a1 = tile[t + 1],        a2 = tile[t + 2];
    int b0 = tile[W_ + t],   b1 = tile[W_ + t + 1],   b2 = tile[W_ + t + 2];
    float* orow = out + ((long long)bc * HO_ + r0) * WO_ + t;
    for (int r = 0; r < rows_out; ++r) {
        const int base = (r + 2) * W_ + t;
        const int c0 = tile[base], c1 = tile[base + 1], c2 = tile[base + 2];
        int best = a0, bm = a0 & ~255;
#define CAND(kk) { const int m = (kk) & ~255; if (m < bm) { bm = m; best = (kk); } }
        CAND(a1) CAND(a2) CAND(b0) CAND(b1) CAND(b2) CAND(c0) CAND(c1) CAND(c2)
#undef CAND
        orow[(long long)r * WO_] = (float)(best & 255);
        a0 = b0; a1 = b1; a2 = b2;
        b0 = c0; b1 = c1; b2 = c2;
    }
}

extern "C" void kernel_launch(void* const* d_in, const int* in_sizes, int n_in,
                              void* d_out, int out_size, void* d_ws, size_t ws_size,
                              hipStream_t stream) {
    const float* x = (const float*)d_in[0];
    float* out = (float*)d_out;
    (void)d_ws; (void)ws_size;

    hist_kernel<<<HBLOCKS, 256, 0, stream>>>(x);
    reduce_kernel<<<8, 256, 0, stream>>>();
    pool_kernel<<<BC_ * 16, 256, 0, stream>>>(out);
}

// Round 2
// 126.784 us; speedup vs baseline: 1.0601x; 1.0601x over previous
//
#include <hip/hip_runtime.h>

// x shape (8,32,256,256) float32 holding exact integers 0..255; K=3, stride 1, no pad.
#define B_   8
#define C_   32
#define H_   256
#define W_   256
#define BC_  (B_ * C_)
#define HO_  (H_ - 2)           // 254
#define WO_  (W_ - 2)           // 254
#define NIN_  (BC_ * H_ * W_)   // 16,777,216
#define NBINS 256
#define HCOLS 16                // sub-histogram columns (LDS-atomic aliasing ~2-way = free)
#define HBLOCKS 1024            // NIN_/4 = HBLOCKS*256*16 exactly

// v6 post-mortem of v5: u8 shadow was a wash — after the harness poison fill sweeps
// L3, hist's 64 MB read of x leaves x L3-resident, so pool's f32 re-read was already
// L3-hot; the shadow just added 17 MB of writes. v6: drop the shadow (hist writes only
// 1 MB of partials), pool reads x directly, and out is stored non-temporally (written
// once, never read — don't evict x's L3 lines during pool).
__device__ int g_hist8[8 * NBINS];        // 8 partial final histograms (reduce output)
__device__ int g_part[HBLOCKS * NBINS];   // 1 MB, fully overwritten each call

__global__ __launch_bounds__(256) void hist_kernel(const float* __restrict__ x) {
    __shared__ int sh[NBINS * HCOLS];   // 16 KB
    const int t = threadIdx.x;
    for (int i = t; i < NBINS * HCOLS; i += 256) sh[i] = 0;
    __syncthreads();

    const int col = t & (HCOLS - 1);
    const float4* x4 = (const float4*)x;
    const int stride = HBLOCKS * 256;          // 262144 float4s
    float4 v[8];
#pragma unroll
    for (int half = 0; half < 2; ++half) {
        const int base = blockIdx.x * 256 + t + half * 8 * stride;
#pragma unroll
        for (int k = 0; k < 8; ++k) v[k] = x4[base + k * stride];  // 8 loads in flight
#pragma unroll
        for (int k = 0; k < 8; ++k) {
            atomicAdd(&sh[((int)v[k].x) * HCOLS + col], 1);
            atomicAdd(&sh[((int)v[k].y) * HCOLS + col], 1);
            atomicAdd(&sh[((int)v[k].z) * HCOLS + col], 1);
            atomicAdd(&sh[((int)v[k].w) * HCOLS + col], 1);
        }
    }
    __syncthreads();

    // Per-bin column sum, rotated so bank = (17t+c) mod 32 (2-way = free); plain store.
    int s0 = 0;
#pragma unroll
    for (int c = 0; c < HCOLS; ++c) {
        const int cc = (c + t) & (HCOLS - 1);
        s0 += sh[t * HCOLS + cc];
    }
    g_part[blockIdx.x * NBINS + t] = s0;
}

// 8 blocks x 256 threads: block j sums partial rows [j*128, j*128+128) (coalesced,
// unroll-8 MLP), then ONE plain store per thread into its own g_hist8 row.
__global__ __launch_bounds__(256) void reduce_kernel() {
    const int t = threadIdx.x;
    const int r0 = blockIdx.x * (HBLOCKS / 8);
    int s = 0;
#pragma unroll 8
    for (int i = 0; i < HBLOCKS / 8; ++i) s += g_part[(r0 + i) * NBINS + t];
    g_hist8[blockIdx.x * NBINS + t] = s;
}

// Block = one (bc, 16-output-row strip). Sum the 8 partial histograms (L2-hot
// broadcast), build key table (key = (count<<8)|value), load 18x256 f32 input tile
// (L3-hot — hist just read x), translate once per input element to keys in LDS.
// Compute reads keys stride-1 (2-way bank alias = free) with 3-register row rotation:
// 3 new LDS reads per output. Argmin on (key & ~255) strict '<' == exact positional
// first-min (row-major di,dj — matches jnp.argmin). Output stored non-temporally.
__global__ __launch_bounds__(256) void pool_kernel(const float* __restrict__ x,
                                                   float* __restrict__ out) {
    __shared__ int key_s[NBINS];
    __shared__ int tile[18 * W_];   // 18 KB
    const int t = threadIdx.x;
    int h = 0;
#pragma unroll
    for (int j = 0; j < 8; ++j) h += g_hist8[j * NBINS + t];
    key_s[t] = (h << 8) | t;
    __syncthreads();

    const int bc = blockIdx.x >> 4;
    const int s  = blockIdx.x & 15;
    const int r0 = s * 16;
    const int rows_out = (r0 + 16 <= HO_) ? 16 : (HO_ - r0);  // 16, last strip 14
    const int rows_in  = rows_out + 2;                        // 18 / 16 (fits H_)

    const float4* xin = (const float4*)(x + ((long long)bc * H_ + r0) * W_);
    const int nf4 = rows_in * (W_ / 4);
    for (int idx = t; idx < nf4; idx += 256) {
        float4 v = xin[idx];
        int4 k;
        k.x = key_s[(int)v.x];
        k.y = key_s[(int)v.y];
        k.z = key_s[(int)v.z];
        k.w = key_s[(int)v.w];
        ((int4*)tile)[idx] = k;
    }
    __syncthreads();

    if (t >= WO_) return;   // no further barriers below

    int a0 = tile[t],        a1 = tile[t + 1],        a2 = tile[t + 2];
    int b0 = tile[W_ + t],   b1 = tile[W_ + t + 1],   b2 = tile[W_ + t + 2];
    float* orow = out + ((long long)bc * HO_ + r0) * WO_ + t;
    for (int r = 0; r < rows_out; ++r) {
        const int base = (r + 2) * W_ + t;
        const int c0 = tile[base], c1 = tile[base + 1], c2 = tile[base + 2];
        int best = a0, bm = a0 & ~255;
#define CAND(kk) { const int m = (kk) & ~255; if (m < bm) { bm = m; best = (kk); } }
        CAND(a1) CAND(a2) CAND(b0) CAND(b1) CAND(b2) CAND(c0) CAND(c1) CAND(c2)
#undef CAND
        __builtin_nontemporal_store((float)(best & 255), &orow[(long long)r * WO_]);
        a0 = b0; a1 = b1; a2 = b2;
        b0 = c0; b1 = c1; b2 = c2;
    }
}

extern "C" void kernel_launch(void* const* d_in, const int* in_sizes, int n_in,
                              void* d_out, int out_size, void* d_ws, size_t ws_size,
                              hipStream_t stream) {
    const float* x = (const float*)d_in[0];
    float* out = (float*)d_out;
    (void)d_ws; (void)ws_size;

    hist_kernel<<<HBLOCKS, 256, 0, stream>>>(x);
    reduce_kernel<<<8, 256, 0, stream>>>();
    pool_kernel<<<BC_ * 16, 256, 0, stream>>>(x, out);
}